// Round 4
// baseline (724.326 us; speedup 1.0000x reference)
//
#include <hip/hip_runtime.h>
#include <hip/hip_bf16.h>
#include <math.h>

#define N_NODES 20000
#define N_EDGES 320000
#define N_GRAPHS 64

typedef __bf16 bf16_t;
typedef bf16_t bf16x8 __attribute__((ext_vector_type(8)));
typedef bf16_t bf16x4 __attribute__((ext_vector_type(4)));
typedef float f32x4 __attribute__((ext_vector_type(4)));

// ---------------------------------------------------------------- CSR build
__global__ void hist_k(const int* __restrict__ dst, int* __restrict__ deg, int E) {
    int e = blockIdx.x * 256 + threadIdx.x;
    if (e < E) atomicAdd(&deg[dst[e]], 1);
}

__global__ void scan_k(const int* __restrict__ deg, int* __restrict__ offs,
                       int* __restrict__ cursor, int n) {
    __shared__ int buf[1024];
    __shared__ int s_carry;
    int tid = threadIdx.x;
    if (tid == 0) s_carry = 0;
    __syncthreads();
    for (int base = 0; base < n; base += 1024) {
        int carry = s_carry;
        int i = base + tid;
        int v = (i < n) ? deg[i] : 0;
        buf[tid] = v;
        __syncthreads();
        for (int off = 1; off < 1024; off <<= 1) {
            int t = (tid >= off) ? buf[tid - off] : 0;
            __syncthreads();
            buf[tid] += t;
            __syncthreads();
        }
        int incl = buf[tid];
        if (i < n) { int ex = carry + incl - v; offs[i] = ex; cursor[i] = ex; }
        if (tid == 1023) s_carry = carry + incl;
        __syncthreads();
    }
    if (tid == 0) offs[n] = s_carry;
}

__global__ void scatter_k(const int* __restrict__ src, const int* __restrict__ dst,
                          int* __restrict__ cursor, int* __restrict__ csr_src,
                          int* __restrict__ csr_eid, int E) {
    int e = blockIdx.x * 256 + threadIdx.x;
    if (e < E) {
        int d = dst[e];
        int p = atomicAdd(&cursor[d], 1);
        csr_src[p] = src[e];
        csr_eid[p] = e;
    }
}

// --------------------------------------------- weight transpose + bf16 cast
__global__ __launch_bounds__(256) void wt_k(const float* __restrict__ W,
                                            bf16_t* __restrict__ Bt, int K, int N) {
    __shared__ float t[32][33];
    int k0 = blockIdx.y * 32, n0 = blockIdx.x * 32;
    int tx = threadIdx.x & 31, ty = threadIdx.x >> 5;
    for (int i = ty; i < 32; i += 8) t[i][tx] = W[(size_t)(k0 + i) * N + n0 + tx];
    __syncthreads();
    for (int i = ty; i < 32; i += 8)
        Bt[(size_t)(n0 + i) * K + k0 + tx] = (bf16_t)t[tx][i];
}

// ------------------------------------- fold attention vectors into weights
// WaT[h][k]   = sum_c W[k, h*C+c] * a_src[h,c]
// WaT[H+h][k] = sum_c W[k, h*C+c] * a_dst[h,c]
__global__ void fold_k(const float* __restrict__ W, const float* __restrict__ a_s,
                       const float* __restrict__ a_d, float* __restrict__ WaT,
                       int K, int H, int C) {
    int k = blockIdx.x * 64 + threadIdx.x;
    if (k >= K) return;
    int HC = H * C;
    for (int h = 0; h < H; ++h) {
        float s = 0.f, d = 0.f;
        for (int c = 0; c < C; ++c) {
            float w = W[(size_t)k * HC + h * C + c];
            s += w * a_s[h * C + c];
            d += w * a_d[h * C + c];
        }
        WaT[h * K + k] = s;
        WaT[(H + h) * K + k] = d;
    }
}

// ---------------------------------------------------------------- fp32 GEMM
// Used only for layer 1 (K=8).
template <typename OUT>
__global__ __launch_bounds__(256) void gemm_k(const float* __restrict__ A,
                                              const float* __restrict__ B,
                                              OUT* __restrict__ C,
                                              const float* __restrict__ bias,
                                              int M, int N, int K) {
    __shared__ float As[16][65];
    __shared__ float Bs[16][64];
    int tid = threadIdx.x;
    int tx = tid & 15, ty = tid >> 4;
    int row0 = blockIdx.y * 64, col0 = blockIdx.x * 64;
    float acc[4][4] = {};
    for (int k0 = 0; k0 < K; k0 += 16) {
        #pragma unroll
        for (int i = 0; i < 4; ++i) {
            int idx = tid + i * 256;
            int m = idx >> 4, kk = idx & 15;
            int gm = row0 + m, gk = k0 + kk;
            As[kk][m] = (gm < M && gk < K) ? A[(size_t)gm * K + gk] : 0.f;
        }
        #pragma unroll
        for (int i = 0; i < 4; ++i) {
            int idx = tid + i * 256;
            int kk = idx >> 6, n = idx & 63;
            int gk = k0 + kk, gn = col0 + n;
            Bs[kk][n] = (gk < K && gn < N) ? B[(size_t)gk * N + gn] : 0.f;
        }
        __syncthreads();
        #pragma unroll
        for (int kk = 0; kk < 16; ++kk) {
            float a[4], b[4];
            #pragma unroll
            for (int i = 0; i < 4; ++i) a[i] = As[kk][ty * 4 + i];
            #pragma unroll
            for (int j = 0; j < 4; ++j) b[j] = Bs[kk][tx * 4 + j];
            #pragma unroll
            for (int i = 0; i < 4; ++i)
                #pragma unroll
                for (int j = 0; j < 4; ++j) acc[i][j] += a[i] * b[j];
        }
        __syncthreads();
    }
    #pragma unroll
    for (int i = 0; i < 4; ++i) {
        int gm = row0 + ty * 4 + i;
        if (gm >= M) continue;
        #pragma unroll
        for (int j = 0; j < 4; ++j) {
            int gn = col0 + tx * 4 + j;
            if (gn < N) C[(size_t)gm * N + gn] = (OUT)(acc[i][j] + (bias ? bias[gn] : 0.f));
        }
    }
}

// ------------------------------------------------------------ bf16 MFMA GEMM
template <typename OUT>
__global__ __launch_bounds__(256) void gemm_bf16_k(
    const bf16_t* __restrict__ A, const bf16_t* __restrict__ Bt,
    OUT* __restrict__ C, const float* __restrict__ bias, int M, int N, int K) {
    __shared__ bf16_t As[128][40];
    __shared__ bf16_t Bs[128][40];
    int tid = threadIdx.x;
    int row0 = blockIdx.y * 128, col0 = blockIdx.x * 128;
    int wave = tid >> 6, lane = tid & 63, quad = lane >> 4, l16 = lane & 15;
    int wm = wave >> 1, wn = wave & 1;
    f32x4 acc[4][4] = {};
    int sr = tid >> 2;
    int sc = (tid & 3) * 8;
    for (int k0 = 0; k0 < K; k0 += 32) {
        #pragma unroll
        for (int half = 0; half < 2; ++half) {
            int r = sr + half * 64;
            int gm = row0 + r;
            bf16x8 v = {};
            if (gm < M) v = *(const bf16x8*)&A[(size_t)gm * K + k0 + sc];
            *(bf16x8*)&As[r][sc] = v;
            int gn = col0 + r;
            bf16x8 w = {};
            if (gn < N) w = *(const bf16x8*)&Bt[(size_t)gn * K + k0 + sc];
            *(bf16x8*)&Bs[r][sc] = w;
        }
        __syncthreads();
        bf16x8 af[4], bfr[4];
        #pragma unroll
        for (int i = 0; i < 4; ++i) {
            af[i] = *(const bf16x8*)&As[wm * 64 + i * 16 + l16][quad * 8];
            bfr[i] = *(const bf16x8*)&Bs[wn * 64 + i * 16 + l16][quad * 8];
        }
        #pragma unroll
        for (int i = 0; i < 4; ++i)
            #pragma unroll
            for (int j = 0; j < 4; ++j)
                acc[i][j] = __builtin_amdgcn_mfma_f32_16x16x32_bf16(af[i], bfr[j],
                                                                   acc[i][j], 0, 0, 0);
        __syncthreads();
    }
    #pragma unroll
    for (int i = 0; i < 4; ++i) {
        int base_m = row0 + wm * 64 + i * 16 + quad * 4;
        #pragma unroll
        for (int j = 0; j < 4; ++j) {
            int gn = col0 + wn * 64 + j * 16 + l16;
            float bv = bias ? bias[gn] : 0.f;
            #pragma unroll
            for (int r = 0; r < 4; ++r) {
                int gm = base_m + r;
                if (gm < M) C[(size_t)gm * N + gn] = (OUT)(acc[i][j][r] + bv);
            }
        }
    }
}

// -------------------------------------------- attention scores via folded W
// Layer 1: x fp32, K=8. One thread per node.
__global__ void scores1_k(const float* __restrict__ x, const float* __restrict__ WaT,
                          float* __restrict__ as_, float* __restrict__ ad_, int N) {
    int j = blockIdx.x * 256 + threadIdx.x;
    if (j >= N) return;
    float xr[8];
    #pragma unroll
    for (int k = 0; k < 8; ++k) xr[k] = x[(size_t)j * 8 + k];
    #pragma unroll
    for (int t = 0; t < 8; ++t) {
        float s = 0.f;
        #pragma unroll
        for (int k = 0; k < 8; ++k) s += xr[k] * WaT[t * 8 + k];
        if (t < 4) as_[j * 4 + t] = s;
        else ad_[j * 4 + (t - 4)] = s;
    }
}

// Layers 2/3: x bf16 [N,256]. One wave per node; acc[2H] fully static.
template <int TWOH>
__global__ __launch_bounds__(256) void scores_k(const bf16_t* __restrict__ xb,
                                                const float* __restrict__ WaT,
                                                float* __restrict__ as_,
                                                float* __restrict__ ad_, int N) {
    int tid = threadIdx.x, wave = tid >> 6, lane = tid & 63;
    int j = blockIdx.x * 4 + wave;
    bf16x4 v = {};
    if (j < N) v = *(const bf16x4*)&xb[(size_t)j * 256 + lane * 4];
    float x0 = (float)v[0], x1 = (float)v[1], x2 = (float)v[2], x3 = (float)v[3];
    float acc[TWOH];
    #pragma unroll
    for (int t = 0; t < TWOH; ++t) {
        f32x4 w = *(const f32x4*)&WaT[t * 256 + lane * 4];
        acc[t] = x0 * w[0] + x1 * w[1] + x2 * w[2] + x3 * w[3];
    }
    #pragma unroll
    for (int off = 32; off; off >>= 1)
        #pragma unroll
        for (int t = 0; t < TWOH; ++t) acc[t] += __shfl_xor(acc[t], off);
    if (lane == 0 && j < N) {
        const int H = TWOH / 2;
        #pragma unroll
        for (int t = 0; t < H; ++t) as_[j * H + t] = acc[t];
        #pragma unroll
        for (int t = 0; t < H; ++t) ad_[j * H + t] = acc[H + t];
    }
}

__device__ __forceinline__ float leaky02(float v) { return v > 0.f ? v : 0.2f * v; }

// ------------------------------------------- aggregation, concat (H=4,C=64)
// 4 edge-slots; each slot: 64 threads x bf16x4 = full 256-ch row per edge.
__global__ __launch_bounds__(256) void agg_concat_k(
    const bf16_t* __restrict__ h, const float* __restrict__ as_,
    const float* __restrict__ ad_, const int* __restrict__ offs,
    const int* __restrict__ csr_src, const float* __restrict__ lin,
    const float* __restrict__ bgat, bf16_t* __restrict__ xb) {
    int j = blockIdx.x;
    int tid = threadIdx.x;  // 256
    int o0 = offs[j], deg = offs[j + 1] - o0;
    __shared__ float s_m[4], s_d[4], s_adj[4];
    __shared__ float s_alpha[64 * 4];
    __shared__ int s_src[64];
    __shared__ float s_red[4][256];
    if (tid < 4) s_adj[tid] = ad_[j * 4 + tid];
    __syncthreads();
    if (tid < 64) {
        float mx[4] = {-3.4e38f, -3.4e38f, -3.4e38f, -3.4e38f};
        for (int e = tid; e < deg; e += 64) {
            int s = csr_src[o0 + e];
            #pragma unroll
            for (int hh = 0; hh < 4; ++hh) {
                float v = leaky02(as_[s * 4 + hh] + s_adj[hh]);
                mx[hh] = fmaxf(mx[hh], v);
            }
        }
        #pragma unroll
        for (int off = 32; off; off >>= 1)
            #pragma unroll
            for (int hh = 0; hh < 4; ++hh) mx[hh] = fmaxf(mx[hh], __shfl_xor(mx[hh], off));
        float sm[4] = {0.f, 0.f, 0.f, 0.f};
        for (int e = tid; e < deg; e += 64) {
            int s = csr_src[o0 + e];
            #pragma unroll
            for (int hh = 0; hh < 4; ++hh) {
                float v = leaky02(as_[s * 4 + hh] + s_adj[hh]);
                sm[hh] += __expf(v - mx[hh]);
            }
        }
        #pragma unroll
        for (int off = 32; off; off >>= 1)
            #pragma unroll
            for (int hh = 0; hh < 4; ++hh) sm[hh] += __shfl_xor(sm[hh], off);
        if (tid == 0) {
            #pragma unroll
            for (int hh = 0; hh < 4; ++hh) { s_m[hh] = mx[hh]; s_d[hh] = sm[hh]; }
        }
    }
    __syncthreads();
    int slot = tid >> 6;
    int l6 = tid & 63;
    int c0 = l6 * 4;
    int myh = l6 >> 4;
    f32x4 acc = {};
    for (int e0 = 0; e0 < deg; e0 += 64) {
        int ne = min(64, deg - e0);
        {
            int e_l = tid >> 2, ah = tid & 3;
            if (e_l < ne) {
                int s = csr_src[o0 + e0 + e_l];
                if (ah == 0) s_src[e_l] = s;
                float v = leaky02(as_[s * 4 + ah] + s_adj[ah]);
                s_alpha[e_l * 4 + ah] = __expf(v - s_m[ah]) / (s_d[ah] + 1e-16f);
            }
        }
        __syncthreads();
        int e_l = slot;
        for (; e_l + 4 < ne; e_l += 8) {
            int s0 = s_src[e_l], s1 = s_src[e_l + 4];
            float a0 = s_alpha[e_l * 4 + myh], a1 = s_alpha[(e_l + 4) * 4 + myh];
            bf16x4 v0 = *(const bf16x4*)&h[(size_t)s0 * 256 + c0];
            bf16x4 v1 = *(const bf16x4*)&h[(size_t)s1 * 256 + c0];
            #pragma unroll
            for (int i = 0; i < 4; ++i) acc[i] += a0 * (float)v0[i];
            #pragma unroll
            for (int i = 0; i < 4; ++i) acc[i] += a1 * (float)v1[i];
        }
        if (e_l < ne) {
            int s0 = s_src[e_l];
            float a0 = s_alpha[e_l * 4 + myh];
            bf16x4 v0 = *(const bf16x4*)&h[(size_t)s0 * 256 + c0];
            #pragma unroll
            for (int i = 0; i < 4; ++i) acc[i] += a0 * (float)v0[i];
        }
        __syncthreads();
    }
    #pragma unroll
    for (int i = 0; i < 4; ++i) s_red[slot][c0 + i] = acc[i];
    __syncthreads();
    if (tid < 64) {
        f32x4 r0 = *(const f32x4*)&s_red[0][c0];
        f32x4 r1 = *(const f32x4*)&s_red[1][c0];
        f32x4 r2 = *(const f32x4*)&s_red[2][c0];
        f32x4 r3 = *(const f32x4*)&s_red[3][c0];
        f32x4 bg = *(const f32x4*)&bgat[c0];
        f32x4 ln = *(const f32x4*)&lin[(size_t)j * 256 + c0];
        bf16x4 o;
        #pragma unroll
        for (int i = 0; i < 4; ++i) {
            float v = fmaxf(r0[i] + r1[i] + r2[i] + r3[i] + bg[i] + ln[i], 0.f);
            o[i] = (bf16_t)v;
        }
        *(bf16x4*)&xb[(size_t)j * 256 + c0] = o;
    }
}

// --------------------------------------- aggregation, mean (H=6,C=128) + att
__global__ __launch_bounds__(256) void agg_mean_k(
    const bf16_t* __restrict__ h, const float* __restrict__ as_,
    const float* __restrict__ ad_, const int* __restrict__ offs,
    const int* __restrict__ csr_src, const int* __restrict__ csr_eid,
    const float* __restrict__ xres, const float* __restrict__ bgat,
    float* __restrict__ y, float* __restrict__ att) {
    int j = blockIdx.x;
    int tid = threadIdx.x;  // 256
    int o0 = offs[j], deg = offs[j + 1] - o0;
    __shared__ float s_m[6], s_d[6], s_adj[6];
    __shared__ float s_alpha[64 * 6];
    __shared__ int s_src[64];
    __shared__ float s_red[6][128];
    if (tid < 6) s_adj[tid] = ad_[j * 6 + tid];
    __syncthreads();
    if (tid < 64) {
        float mx[6], sm[6];
        #pragma unroll
        for (int hh = 0; hh < 6; ++hh) { mx[hh] = -3.4e38f; sm[hh] = 0.f; }
        for (int e = tid; e < deg; e += 64) {
            int s = csr_src[o0 + e];
            #pragma unroll
            for (int hh = 0; hh < 6; ++hh) {
                float v = leaky02(as_[s * 6 + hh] + s_adj[hh]);
                mx[hh] = fmaxf(mx[hh], v);
            }
        }
        #pragma unroll
        for (int off = 32; off; off >>= 1)
            #pragma unroll
            for (int hh = 0; hh < 6; ++hh) mx[hh] = fmaxf(mx[hh], __shfl_xor(mx[hh], off));
        for (int e = tid; e < deg; e += 64) {
            int s = csr_src[o0 + e];
            #pragma unroll
            for (int hh = 0; hh < 6; ++hh) {
                float v = leaky02(as_[s * 6 + hh] + s_adj[hh]);
                sm[hh] += __expf(v - mx[hh]);
            }
        }
        #pragma unroll
        for (int off = 32; off; off >>= 1)
            #pragma unroll
            for (int hh = 0; hh < 6; ++hh) sm[hh] += __shfl_xor(sm[hh], off);
        if (tid == 0) {
            #pragma unroll
            for (int hh = 0; hh < 6; ++hh) { s_m[hh] = mx[hh]; s_d[hh] = sm[hh]; }
        }
    }
    __syncthreads();
    int ghh = tid >> 5;           // 0..7 (6 used)
    int c0 = (tid & 31) * 4;      // 0..124
    f32x4 acc = {};
    for (int e0 = 0; e0 < deg; e0 += 64) {
        int ne = min(64, deg - e0);
        for (int i = tid; i < ne * 6; i += 256) {
            int e_l = i / 6, ah = i - e_l * 6;
            int p = o0 + e0 + e_l;
            int s = csr_src[p];
            if (ah == 0) s_src[e_l] = s;
            float v = leaky02(as_[s * 6 + ah] + s_adj[ah]);
            float al = __expf(v - s_m[ah]) / (s_d[ah] + 1e-16f);
            s_alpha[e_l * 6 + ah] = al;
            att[(size_t)csr_eid[p] * 6 + ah] = al;
        }
        __syncthreads();
        if (ghh < 6) {
            int e_l = 0;
            for (; e_l + 1 < ne; e_l += 2) {
                int s0 = s_src[e_l], s1 = s_src[e_l + 1];
                float a0 = s_alpha[e_l * 6 + ghh], a1 = s_alpha[(e_l + 1) * 6 + ghh];
                bf16x4 v0 = *(const bf16x4*)&h[(size_t)s0 * 768 + ghh * 128 + c0];
                bf16x4 v1 = *(const bf16x4*)&h[(size_t)s1 * 768 + ghh * 128 + c0];
                #pragma unroll
                for (int i = 0; i < 4; ++i) acc[i] += a0 * (float)v0[i];
                #pragma unroll
                for (int i = 0; i < 4; ++i) acc[i] += a1 * (float)v1[i];
            }
            if (e_l < ne) {
                int s0 = s_src[e_l];
                float a0 = s_alpha[e_l * 6 + ghh];
                bf16x4 v0 = *(const bf16x4*)&h[(size_t)s0 * 768 + ghh * 128 + c0];
                #pragma unroll
                for (int i = 0; i < 4; ++i) acc[i] += a0 * (float)v0[i];
            }
        }
        __syncthreads();
    }
    if (ghh < 6) {
        #pragma unroll
        for (int i = 0; i < 4; ++i) s_red[ghh][c0 + i] = acc[i];
    }
    __syncthreads();
    if (tid < 128) {
        float s = 0.f;
        #pragma unroll
        for (int hh = 0; hh < 6; ++hh) s += s_red[hh][tid];
        y[(size_t)j * 128 + tid] =
            fmaxf(s * (1.f / 6.f) + bgat[tid] + xres[(size_t)j * 128 + tid], 0.f);
    }
}

// ---------------------------------------------------------------- BatchNorm
__global__ void bn_stats_k(const float* __restrict__ y, float* __restrict__ sums, int N) {
    int c = threadIdx.x;  // 128
    float s = 0.f, q = 0.f;
    for (int r = blockIdx.x; r < N; r += gridDim.x) {
        float v = y[(size_t)r * 128 + c];
        s += v;
        q += v * v;
    }
    atomicAdd(&sums[c], s);
    atomicAdd(&sums[128 + c], q);
}
__global__ void bn_scale_k(const float* __restrict__ sums, const float* __restrict__ gamma,
                           const float* __restrict__ beta, float* __restrict__ scale,
                           float* __restrict__ shift, int N) {
    int c = threadIdx.x;
    float mu = sums[c] / (float)N;
    float var = fmaxf(sums[128 + c] / (float)N - mu * mu, 0.f);
    float inv = rsqrtf(var + 1e-5f) * gamma[c];
    scale[c] = inv;
    shift[c] = beta[c] - mu * inv;
}

// ---------------------------------------------------------------- max pool
__device__ __forceinline__ unsigned f2key(float f) {
    unsigned b = __float_as_uint(f);
    return (b & 0x80000000u) ? ~b : (b | 0x80000000u);
}
__global__ void pool_init_k(unsigned* __restrict__ pool_u) {
    int i = blockIdx.x * 256 + threadIdx.x;
    if (i < N_GRAPHS * 128) pool_u[i] = f2key(-3.402823466e38f * 2.0f);
}
__global__ void norm_pool_k(const float* __restrict__ y, const float* __restrict__ scale,
                            const float* __restrict__ shift, const int* __restrict__ batch,
                            unsigned* __restrict__ pool_u, int N) {
    int idx = blockIdx.x * 256 + threadIdx.x;
    if (idx >= N * 128) return;
    int n = idx >> 7, c = idx & 127;
    float v = y[idx] * scale[c] + shift[c];
    atomicMax(&pool_u[batch[n] * 128 + c], f2key(v));
}
__global__ void pool_write_k(const unsigned* __restrict__ pool_u, float* __restrict__ out) {
    int i = blockIdx.x * 256 + threadIdx.x;
    if (i < N_GRAPHS * 128) {
        unsigned u = pool_u[i];
        unsigned b = (u & 0x80000000u) ? (u & 0x7FFFFFFFu) : ~u;
        out[i] = __uint_as_float(b);
    }
}

// ================================================================ launcher
extern "C" void kernel_launch(void* const* d_in, const int* in_sizes, int n_in,
                              void* d_out, int out_size, void* d_ws, size_t ws_size,
                              hipStream_t stream) {
    const int N = N_NODES, E = N_EDGES;
    const float* x_ppi = (const float*)d_in[0];
    const int* edge = (const int*)d_in[1];
    const int* batch = (const int*)d_in[2];
    const float* W1 = (const float*)d_in[3];
    const float* a_src1 = (const float*)d_in[4];
    const float* a_dst1 = (const float*)d_in[5];
    const float* b_gat1 = (const float*)d_in[6];
    const float* lw1 = (const float*)d_in[7];
    const float* lb1 = (const float*)d_in[8];
    const float* W2 = (const float*)d_in[9];
    const float* a_src2 = (const float*)d_in[10];
    const float* a_dst2 = (const float*)d_in[11];
    const float* b_gat2 = (const float*)d_in[12];
    const float* lw2 = (const float*)d_in[13];
    const float* lb2 = (const float*)d_in[14];
    const float* W3 = (const float*)d_in[15];
    const float* a_src3 = (const float*)d_in[16];
    const float* a_dst3 = (const float*)d_in[17];
    const float* b_gat3 = (const float*)d_in[18];
    const float* lw3 = (const float*)d_in[19];
    const float* lb3 = (const float*)d_in[20];
    const float* bn_gamma = (const float*)d_in[21];
    const float* bn_beta = (const float*)d_in[22];

    const int* src = edge;
    const int* dst = edge + E;

    size_t off = 0;
    auto alloc = [&](size_t bytes) {
        size_t o = off;
        off = (off + bytes + 255) & ~(size_t)255;
        return o;
    };
    char* ws = (char*)d_ws;
    bf16_t* xb = (bf16_t*)(ws + alloc((size_t)N * 256 * 2));
    bf16_t* hb = (bf16_t*)(ws + alloc((size_t)N * 768 * 2));
    float* lin = (float*)(ws + alloc((size_t)N * 256 * 4));
    float* x_res = (float*)(ws + alloc((size_t)N * 128 * 4));
    float* as_ = (float*)(ws + alloc((size_t)N * 6 * 4));
    float* ad_ = (float*)(ws + alloc((size_t)N * 6 * 4));
    int* deg = (int*)(ws + alloc((size_t)(N + 1) * 4));
    int* offs = (int*)(ws + alloc((size_t)(N + 1) * 4));
    int* cursor = (int*)(ws + alloc((size_t)(N + 1) * 4));
    int* csr_src = (int*)(ws + alloc((size_t)E * 4));
    int* csr_eid = (int*)(ws + alloc((size_t)E * 4));
    bf16_t* Wt2 = (bf16_t*)(ws + alloc((size_t)256 * 256 * 2));
    bf16_t* lwt2 = (bf16_t*)(ws + alloc((size_t)256 * 256 * 2));
    bf16_t* Wt3 = (bf16_t*)(ws + alloc((size_t)768 * 256 * 2));
    bf16_t* lwt3 = (bf16_t*)(ws + alloc((size_t)128 * 256 * 2));
    float* WaT1 = (float*)(ws + alloc(64 * 4));
    float* WaT2 = (float*)(ws + alloc(2048 * 4));
    float* WaT3 = (float*)(ws + alloc(3072 * 4));
    float* bn_sums = (float*)(ws + alloc(256 * 4));
    float* bn_scale = (float*)(ws + alloc(128 * 4));
    float* bn_shift = (float*)(ws + alloc(128 * 4));
    unsigned* pool_u = (unsigned*)(ws + alloc((size_t)N_GRAPHS * 128 * 4));

    float* out_pool = (float*)d_out;
    float* out_att = (float*)d_out + N_GRAPHS * 128;

    // ---- CSR + weight prep (independent)
    hipMemsetAsync(deg, 0, (size_t)N * 4, stream);
    hist_k<<<(E + 255) / 256, 256, 0, stream>>>(dst, deg, E);
    scan_k<<<1, 1024, 0, stream>>>(deg, offs, cursor, N);
    scatter_k<<<(E + 255) / 256, 256, 0, stream>>>(src, dst, cursor, csr_src, csr_eid, E);
    wt_k<<<dim3(8, 8), 256, 0, stream>>>(W2, Wt2, 256, 256);
    wt_k<<<dim3(8, 8), 256, 0, stream>>>(lw2, lwt2, 256, 256);
    wt_k<<<dim3(24, 8), 256, 0, stream>>>(W3, Wt3, 256, 768);
    wt_k<<<dim3(4, 8), 256, 0, stream>>>(lw3, lwt3, 256, 128);
    fold_k<<<1, 64, 0, stream>>>(W1, a_src1, a_dst1, WaT1, 8, 4, 64);
    fold_k<<<4, 64, 0, stream>>>(W2, a_src2, a_dst2, WaT2, 256, 4, 64);
    fold_k<<<4, 64, 0, stream>>>(W3, a_src3, a_dst3, WaT3, 256, 6, 128);

    // ---- Layer 1 (in=8, fp32 GEMM — tiny K)
    gemm_k<bf16_t><<<dim3(4, 313), 256, 0, stream>>>(x_ppi, W1, hb, nullptr, N, 256, 8);
    gemm_k<float><<<dim3(4, 313), 256, 0, stream>>>(x_ppi, lw1, lin, lb1, N, 256, 8);
    scores1_k<<<(N + 255) / 256, 256, 0, stream>>>(x_ppi, WaT1, as_, ad_, N);
    agg_concat_k<<<N, 256, 0, stream>>>(hb, as_, ad_, offs, csr_src, lin, b_gat1, xb);

    // ---- Layer 2 (256 -> 256, bf16 MFMA)
    gemm_bf16_k<bf16_t><<<dim3(2, 157), 256, 0, stream>>>(xb, Wt2, hb, nullptr, N, 256, 256);
    gemm_bf16_k<float><<<dim3(2, 157), 256, 0, stream>>>(xb, lwt2, lin, lb2, N, 256, 256);
    scores_k<8><<<(N + 3) / 4, 256, 0, stream>>>(xb, WaT2, as_, ad_, N);
    agg_concat_k<<<N, 256, 0, stream>>>(hb, as_, ad_, offs, csr_src, lin, b_gat2, xb);

    // ---- Layer 3 (256 -> 6x128 mean + residual, bf16 MFMA)
    gemm_bf16_k<bf16_t><<<dim3(6, 157), 256, 0, stream>>>(xb, Wt3, hb, nullptr, N, 768, 256);
    gemm_bf16_k<float><<<dim3(1, 157), 256, 0, stream>>>(xb, lwt3, x_res, lb3, N, 128, 256);
    scores_k<12><<<(N + 3) / 4, 256, 0, stream>>>(xb, WaT3, as_, ad_, N);
    float* y = lin;  // reuse
    agg_mean_k<<<N, 256, 0, stream>>>(hb, as_, ad_, offs, csr_src, csr_eid, x_res, b_gat3,
                                      y, out_att);

    // ---- BatchNorm (training stats, fused sum+sumsq pass)
    hipMemsetAsync(bn_sums, 0, 256 * 4, stream);
    bn_stats_k<<<160, 128, 0, stream>>>(y, bn_sums, N);
    bn_scale_k<<<1, 128, 0, stream>>>(bn_sums, bn_gamma, bn_beta, bn_scale, bn_shift, N);

    // ---- normalize + global max pool
    pool_init_k<<<(N_GRAPHS * 128 + 255) / 256, 256, 0, stream>>>(pool_u);
    norm_pool_k<<<((size_t)N * 128 + 255) / 256, 256, 0, stream>>>(y, bn_scale, bn_shift, batch,
                                                                   pool_u, N);
    pool_write_k<<<(N_GRAPHS * 128 + 255) / 256, 256, 0, stream>>>(pool_u, out_pool);
}

// Round 5
// 706.469 us; speedup vs baseline: 1.0253x; 1.0253x over previous
//
#include <hip/hip_runtime.h>
#include <hip/hip_bf16.h>
#include <math.h>

#define N_NODES 20000
#define N_EDGES 320000
#define N_GRAPHS 64

typedef __bf16 bf16_t;
typedef bf16_t bf16x8 __attribute__((ext_vector_type(8)));
typedef bf16_t bf16x4 __attribute__((ext_vector_type(4)));
typedef float f32x4 __attribute__((ext_vector_type(4)));

// ---------------------------------------------------------------- CSR build
__global__ void hist_k(const int* __restrict__ dst, int* __restrict__ deg, int E) {
    int e = blockIdx.x * 256 + threadIdx.x;
    if (e < E) atomicAdd(&deg[dst[e]], 1);
}

__global__ void scan_k(const int* __restrict__ deg, int* __restrict__ offs,
                       int* __restrict__ cursor, int n) {
    __shared__ int buf[1024];
    __shared__ int s_carry;
    int tid = threadIdx.x;
    if (tid == 0) s_carry = 0;
    __syncthreads();
    for (int base = 0; base < n; base += 1024) {
        int carry = s_carry;
        int i = base + tid;
        int v = (i < n) ? deg[i] : 0;
        buf[tid] = v;
        __syncthreads();
        for (int off = 1; off < 1024; off <<= 1) {
            int t = (tid >= off) ? buf[tid - off] : 0;
            __syncthreads();
            buf[tid] += t;
            __syncthreads();
        }
        int incl = buf[tid];
        if (i < n) { int ex = carry + incl - v; offs[i] = ex; cursor[i] = ex; }
        if (tid == 1023) s_carry = carry + incl;
        __syncthreads();
    }
    if (tid == 0) offs[n] = s_carry;
}

__global__ void scatter_k(const int* __restrict__ src, const int* __restrict__ dst,
                          int* __restrict__ cursor, int* __restrict__ csr_src,
                          int* __restrict__ csr_eid, int E) {
    int e = blockIdx.x * 256 + threadIdx.x;
    if (e < E) {
        int d = dst[e];
        int p = atomicAdd(&cursor[d], 1);
        csr_src[p] = src[e];
        csr_eid[p] = e;
    }
}

// --------------------------------------------- weight transpose + bf16 cast
__global__ __launch_bounds__(256) void wt_k(const float* __restrict__ W,
                                            bf16_t* __restrict__ Bt, int K, int N) {
    __shared__ float t[32][33];
    int k0 = blockIdx.y * 32, n0 = blockIdx.x * 32;
    int tx = threadIdx.x & 31, ty = threadIdx.x >> 5;
    for (int i = ty; i < 32; i += 8) t[i][tx] = W[(size_t)(k0 + i) * N + n0 + tx];
    __syncthreads();
    for (int i = ty; i < 32; i += 8)
        Bt[(size_t)(n0 + i) * K + k0 + tx] = (bf16_t)t[tx][i];
}

// ------------------------------------- fold attention vectors into weights
__global__ void fold_k(const float* __restrict__ W, const float* __restrict__ a_s,
                       const float* __restrict__ a_d, float* __restrict__ WaT,
                       int K, int H, int C) {
    int k = blockIdx.x * 64 + threadIdx.x;
    if (k >= K) return;
    int HC = H * C;
    for (int h = 0; h < H; ++h) {
        float s = 0.f, d = 0.f;
        for (int c = 0; c < C; ++c) {
            float w = W[(size_t)k * HC + h * C + c];
            s += w * a_s[h * C + c];
            d += w * a_d[h * C + c];
        }
        WaT[h * K + k] = s;
        WaT[(H + h) * K + k] = d;
    }
}

// ----------------------- prep: layer-1 fused transform matrix [40,256] fp32
// rows 0..31 = block-diag W1 per head (row h*8+k -> cols h*64..h*64+63),
// rows 32..39 = lw1. bias = b_gat1 + lb1.
__global__ void b1prep_k(const float* __restrict__ W1, const float* __restrict__ lw1,
                         const float* __restrict__ bg, const float* __restrict__ lb,
                         float* __restrict__ B1, float* __restrict__ bb1) {
    int t = threadIdx.x;  // 256, one block
    for (int i = 0; i < 32; ++i) {
        int h = i >> 3, k = i & 7;
        B1[i * 256 + t] = ((t >> 6) == h) ? W1[k * 256 + t] : 0.f;
    }
    for (int k = 0; k < 8; ++k) B1[(32 + k) * 256 + t] = lw1[k * 256 + t];
    bb1[t] = bg[t] + lb[t];
}

// ----------------------- prep: layer-3 fused Bt [128][1792] bf16
// k-index h*256+kk -> W3[kk][h*128+c]/6 ; 1536+kk -> lw3[kk][c]. bias = b_gat3+lb3.
__global__ void b3prep_k(const float* __restrict__ W3, const float* __restrict__ lw3,
                         const float* __restrict__ bg, const float* __restrict__ lb,
                         bf16_t* __restrict__ Bt, float* __restrict__ bb) {
    int c = blockIdx.x;  // 0..127
    for (int idx = threadIdx.x; idx < 1792; idx += 256) {
        float v;
        if (idx < 1536) {
            int h = idx >> 8, k = idx & 255;
            v = W3[(size_t)k * 768 + h * 128 + c] * (1.f / 6.f);
        } else {
            int k = idx - 1536;
            v = lw3[(size_t)k * 128 + c];
        }
        Bt[(size_t)c * 1792 + idx] = (bf16_t)v;
    }
    if (threadIdx.x == 0) bb[c] = bg[c] + lb[c];
}

// ---------------------------------------------------------------- fp32 GEMM
template <typename OUT, bool RELU>
__global__ __launch_bounds__(256) void gemm_k(const float* __restrict__ A,
                                              const float* __restrict__ B,
                                              OUT* __restrict__ C,
                                              const float* __restrict__ bias,
                                              int M, int N, int K) {
    __shared__ float As[16][65];
    __shared__ float Bs[16][64];
    int tid = threadIdx.x;
    int tx = tid & 15, ty = tid >> 4;
    int row0 = blockIdx.y * 64, col0 = blockIdx.x * 64;
    float acc[4][4] = {};
    for (int k0 = 0; k0 < K; k0 += 16) {
        #pragma unroll
        for (int i = 0; i < 4; ++i) {
            int idx = tid + i * 256;
            int m = idx >> 4, kk = idx & 15;
            int gm = row0 + m, gk = k0 + kk;
            As[kk][m] = (gm < M && gk < K) ? A[(size_t)gm * K + gk] : 0.f;
        }
        #pragma unroll
        for (int i = 0; i < 4; ++i) {
            int idx = tid + i * 256;
            int kk = idx >> 6, n = idx & 63;
            int gk = k0 + kk, gn = col0 + n;
            Bs[kk][n] = (gk < K && gn < N) ? B[(size_t)gk * N + gn] : 0.f;
        }
        __syncthreads();
        #pragma unroll
        for (int kk = 0; kk < 16; ++kk) {
            float a[4], b[4];
            #pragma unroll
            for (int i = 0; i < 4; ++i) a[i] = As[kk][ty * 4 + i];
            #pragma unroll
            for (int j = 0; j < 4; ++j) b[j] = Bs[kk][tx * 4 + j];
            #pragma unroll
            for (int i = 0; i < 4; ++i)
                #pragma unroll
                for (int j = 0; j < 4; ++j) acc[i][j] += a[i] * b[j];
        }
        __syncthreads();
    }
    #pragma unroll
    for (int i = 0; i < 4; ++i) {
        int gm = row0 + ty * 4 + i;
        if (gm >= M) continue;
        #pragma unroll
        for (int j = 0; j < 4; ++j) {
            int gn = col0 + tx * 4 + j;
            if (gn < N) {
                float v = acc[i][j] + (bias ? bias[gn] : 0.f);
                if (RELU) v = fmaxf(v, 0.f);
                C[(size_t)gm * N + gn] = (OUT)v;
            }
        }
    }
}

// ------------------------------------------------------------ bf16 MFMA GEMM
template <typename OUT, bool RELU>
__global__ __launch_bounds__(256) void gemm_bf16_k(
    const bf16_t* __restrict__ A, const bf16_t* __restrict__ Bt,
    OUT* __restrict__ C, const float* __restrict__ bias, int M, int N, int K) {
    __shared__ bf16_t As[128][40];
    __shared__ bf16_t Bs[128][40];
    int tid = threadIdx.x;
    int row0 = blockIdx.y * 128, col0 = blockIdx.x * 128;
    int wave = tid >> 6, lane = tid & 63, quad = lane >> 4, l16 = lane & 15;
    int wm = wave >> 1, wn = wave & 1;
    f32x4 acc[4][4] = {};
    int sr = tid >> 2;
    int sc = (tid & 3) * 8;
    for (int k0 = 0; k0 < K; k0 += 32) {
        #pragma unroll
        for (int half = 0; half < 2; ++half) {
            int r = sr + half * 64;
            int gm = row0 + r;
            bf16x8 v = {};
            if (gm < M) v = *(const bf16x8*)&A[(size_t)gm * K + k0 + sc];
            *(bf16x8*)&As[r][sc] = v;
            int gn = col0 + r;
            bf16x8 w = {};
            if (gn < N) w = *(const bf16x8*)&Bt[(size_t)gn * K + k0 + sc];
            *(bf16x8*)&Bs[r][sc] = w;
        }
        __syncthreads();
        bf16x8 af[4], bfr[4];
        #pragma unroll
        for (int i = 0; i < 4; ++i) {
            af[i] = *(const bf16x8*)&As[wm * 64 + i * 16 + l16][quad * 8];
            bfr[i] = *(const bf16x8*)&Bs[wn * 64 + i * 16 + l16][quad * 8];
        }
        #pragma unroll
        for (int i = 0; i < 4; ++i)
            #pragma unroll
            for (int j = 0; j < 4; ++j)
                acc[i][j] = __builtin_amdgcn_mfma_f32_16x16x32_bf16(af[i], bfr[j],
                                                                   acc[i][j], 0, 0, 0);
        __syncthreads();
    }
    #pragma unroll
    for (int i = 0; i < 4; ++i) {
        int base_m = row0 + wm * 64 + i * 16 + quad * 4;
        #pragma unroll
        for (int j = 0; j < 4; ++j) {
            int gn = col0 + wn * 64 + j * 16 + l16;
            float bv = bias ? bias[gn] : 0.f;
            #pragma unroll
            for (int r = 0; r < 4; ++r) {
                int gm = base_m + r;
                if (gm < M) {
                    float v = acc[i][j][r] + bv;
                    if (RELU) v = fmaxf(v, 0.f);
                    C[(size_t)gm * N + gn] = (OUT)v;
                }
            }
        }
    }
}

// -------------------------------------------- attention scores via folded W
__global__ void scores1_k(const float* __restrict__ x, const float* __restrict__ WaT,
                          float* __restrict__ as_, float* __restrict__ ad_, int N) {
    int j = blockIdx.x * 256 + threadIdx.x;
    if (j >= N) return;
    float xr[8];
    #pragma unroll
    for (int k = 0; k < 8; ++k) xr[k] = x[(size_t)j * 8 + k];
    #pragma unroll
    for (int t = 0; t < 8; ++t) {
        float s = 0.f;
        #pragma unroll
        for (int k = 0; k < 8; ++k) s += xr[k] * WaT[t * 8 + k];
        if (t < 4) as_[j * 4 + t] = s;
        else ad_[j * 4 + (t - 4)] = s;
    }
}

template <int TWOH>
__global__ __launch_bounds__(256) void scores_k(const bf16_t* __restrict__ xb,
                                                const float* __restrict__ WaT,
                                                float* __restrict__ as_,
                                                float* __restrict__ ad_, int N) {
    int tid = threadIdx.x, wave = tid >> 6, lane = tid & 63;
    int j = blockIdx.x * 4 + wave;
    bf16x4 v = {};
    if (j < N) v = *(const bf16x4*)&xb[(size_t)j * 256 + lane * 4];
    float x0 = (float)v[0], x1 = (float)v[1], x2 = (float)v[2], x3 = (float)v[3];
    float acc[TWOH];
    #pragma unroll
    for (int t = 0; t < TWOH; ++t) {
        f32x4 w = *(const f32x4*)&WaT[t * 256 + lane * 4];
        acc[t] = x0 * w[0] + x1 * w[1] + x2 * w[2] + x3 * w[3];
    }
    #pragma unroll
    for (int off = 32; off; off >>= 1)
        #pragma unroll
        for (int t = 0; t < TWOH; ++t) acc[t] += __shfl_xor(acc[t], off);
    if (lane == 0 && j < N) {
        const int H = TWOH / 2;
        #pragma unroll
        for (int t = 0; t < H; ++t) as_[j * H + t] = acc[t];
        #pragma unroll
        for (int t = 0; t < H; ++t) ad_[j * H + t] = acc[H + t];
    }
}

__device__ __forceinline__ float leaky02(float v) { return v > 0.f ? v : 0.2f * v; }

// -------------------------- layer-1 x-aggregation (H=4, x 8-wide) -> [N,40]
// One wave per node. xagg[j][h*8+k] = sum_e alpha[e,h]*x[src][k]; tail = x[j].
__global__ __launch_bounds__(256) void agg1_k(
    const float* __restrict__ x, const float* __restrict__ as_,
    const float* __restrict__ ad_, const int* __restrict__ offs,
    const int* __restrict__ csr_src, float* __restrict__ xagg) {
    int wave = threadIdx.x >> 6, lane = threadIdx.x & 63;
    int j = blockIdx.x * 4 + wave;
    if (j >= N_NODES) return;
    int o0 = offs[j], deg = offs[j + 1] - o0;
    float adj0 = ad_[j * 4 + 0], adj1 = ad_[j * 4 + 1];
    float adj2 = ad_[j * 4 + 2], adj3 = ad_[j * 4 + 3];
    float mx[4] = {-3.4e38f, -3.4e38f, -3.4e38f, -3.4e38f};
    for (int e = lane; e < deg; e += 64) {
        int s = csr_src[o0 + e];
        mx[0] = fmaxf(mx[0], leaky02(as_[s * 4 + 0] + adj0));
        mx[1] = fmaxf(mx[1], leaky02(as_[s * 4 + 1] + adj1));
        mx[2] = fmaxf(mx[2], leaky02(as_[s * 4 + 2] + adj2));
        mx[3] = fmaxf(mx[3], leaky02(as_[s * 4 + 3] + adj3));
    }
    #pragma unroll
    for (int off = 32; off; off >>= 1)
        #pragma unroll
        for (int hh = 0; hh < 4; ++hh) mx[hh] = fmaxf(mx[hh], __shfl_xor(mx[hh], off));
    float sm[4] = {0.f, 0.f, 0.f, 0.f};
    for (int e = lane; e < deg; e += 64) {
        int s = csr_src[o0 + e];
        sm[0] += __expf(leaky02(as_[s * 4 + 0] + adj0) - mx[0]);
        sm[1] += __expf(leaky02(as_[s * 4 + 1] + adj1) - mx[1]);
        sm[2] += __expf(leaky02(as_[s * 4 + 2] + adj2) - mx[2]);
        sm[3] += __expf(leaky02(as_[s * 4 + 3] + adj3) - mx[3]);
    }
    #pragma unroll
    for (int off = 32; off; off >>= 1)
        #pragma unroll
        for (int hh = 0; hh < 4; ++hh) sm[hh] += __shfl_xor(sm[hh], off);
    int half = lane >> 5, l = lane & 31, h = l >> 3, k = l & 7;
    float adj_s = (h < 2) ? (h == 0 ? adj0 : adj1) : (h == 2 ? adj2 : adj3);
    float m_s = (h < 2) ? (h == 0 ? mx[0] : mx[1]) : (h == 2 ? mx[2] : mx[3]);
    float d_s = (h < 2) ? (h == 0 ? sm[0] : sm[1]) : (h == 2 ? sm[2] : sm[3]);
    float rd_s = 1.f / (d_s + 1e-16f);
    float acc = 0.f;
    for (int e = half; e < deg; e += 2) {
        int s = csr_src[o0 + e];
        float a = __expf(leaky02(as_[s * 4 + h] + adj_s) - m_s) * rd_s;
        acc += a * x[(size_t)s * 8 + k];
    }
    acc += __shfl_xor(acc, 32);
    if (lane < 32) xagg[(size_t)j * 40 + lane] = acc;
    else if (lane < 40) xagg[(size_t)j * 40 + lane] = x[(size_t)j * 8 + (lane - 32)];
}

// ------------------------------------------- aggregation, concat (H=4,C=64)
__global__ __launch_bounds__(256) void agg_concat_k(
    const bf16_t* __restrict__ h, const float* __restrict__ as_,
    const float* __restrict__ ad_, const int* __restrict__ offs,
    const int* __restrict__ csr_src, const float* __restrict__ lin,
    const float* __restrict__ bgat, bf16_t* __restrict__ xb) {
    int j = blockIdx.x;
    int tid = threadIdx.x;  // 256
    int o0 = offs[j], deg = offs[j + 1] - o0;
    __shared__ float s_m[4], s_d[4], s_adj[4];
    __shared__ float s_alpha[64 * 4];
    __shared__ int s_src[64];
    __shared__ float s_red[4][256];
    if (tid < 4) s_adj[tid] = ad_[j * 4 + tid];
    __syncthreads();
    if (tid < 64) {
        float mx[4] = {-3.4e38f, -3.4e38f, -3.4e38f, -3.4e38f};
        for (int e = tid; e < deg; e += 64) {
            int s = csr_src[o0 + e];
            #pragma unroll
            for (int hh = 0; hh < 4; ++hh) {
                float v = leaky02(as_[s * 4 + hh] + s_adj[hh]);
                mx[hh] = fmaxf(mx[hh], v);
            }
        }
        #pragma unroll
        for (int off = 32; off; off >>= 1)
            #pragma unroll
            for (int hh = 0; hh < 4; ++hh) mx[hh] = fmaxf(mx[hh], __shfl_xor(mx[hh], off));
        float sm[4] = {0.f, 0.f, 0.f, 0.f};
        for (int e = tid; e < deg; e += 64) {
            int s = csr_src[o0 + e];
            #pragma unroll
            for (int hh = 0; hh < 4; ++hh) {
                float v = leaky02(as_[s * 4 + hh] + s_adj[hh]);
                sm[hh] += __expf(v - mx[hh]);
            }
        }
        #pragma unroll
        for (int off = 32; off; off >>= 1)
            #pragma unroll
            for (int hh = 0; hh < 4; ++hh) sm[hh] += __shfl_xor(sm[hh], off);
        if (tid == 0) {
            #pragma unroll
            for (int hh = 0; hh < 4; ++hh) { s_m[hh] = mx[hh]; s_d[hh] = sm[hh]; }
        }
    }
    __syncthreads();
    int slot = tid >> 6;
    int l6 = tid & 63;
    int c0 = l6 * 4;
    int myh = l6 >> 4;
    f32x4 acc = {};
    for (int e0 = 0; e0 < deg; e0 += 64) {
        int ne = min(64, deg - e0);
        {
            int e_l = tid >> 2, ah = tid & 3;
            if (e_l < ne) {
                int s = csr_src[o0 + e0 + e_l];
                if (ah == 0) s_src[e_l] = s;
                float v = leaky02(as_[s * 4 + ah] + s_adj[ah]);
                s_alpha[e_l * 4 + ah] = __expf(v - s_m[ah]) / (s_d[ah] + 1e-16f);
            }
        }
        __syncthreads();
        int e_l = slot;
        for (; e_l + 4 < ne; e_l += 8) {
            int s0 = s_src[e_l], s1 = s_src[e_l + 4];
            float a0 = s_alpha[e_l * 4 + myh], a1 = s_alpha[(e_l + 4) * 4 + myh];
            bf16x4 v0 = *(const bf16x4*)&h[(size_t)s0 * 256 + c0];
            bf16x4 v1 = *(const bf16x4*)&h[(size_t)s1 * 256 + c0];
            #pragma unroll
            for (int i = 0; i < 4; ++i) acc[i] += a0 * (float)v0[i];
            #pragma unroll
            for (int i = 0; i < 4; ++i) acc[i] += a1 * (float)v1[i];
        }
        if (e_l < ne) {
            int s0 = s_src[e_l];
            float a0 = s_alpha[e_l * 4 + myh];
            bf16x4 v0 = *(const bf16x4*)&h[(size_t)s0 * 256 + c0];
            #pragma unroll
            for (int i = 0; i < 4; ++i) acc[i] += a0 * (float)v0[i];
        }
        __syncthreads();
    }
    #pragma unroll
    for (int i = 0; i < 4; ++i) s_red[slot][c0 + i] = acc[i];
    __syncthreads();
    if (tid < 64) {
        f32x4 r0 = *(const f32x4*)&s_red[0][c0];
        f32x4 r1 = *(const f32x4*)&s_red[1][c0];
        f32x4 r2 = *(const f32x4*)&s_red[2][c0];
        f32x4 r3 = *(const f32x4*)&s_red[3][c0];
        f32x4 bg = *(const f32x4*)&bgat[c0];
        f32x4 ln = *(const f32x4*)&lin[(size_t)j * 256 + c0];
        bf16x4 o;
        #pragma unroll
        for (int i = 0; i < 4; ++i) {
            float v = fmaxf(r0[i] + r1[i] + r2[i] + r3[i] + bg[i] + ln[i], 0.f);
            o[i] = (bf16_t)v;
        }
        *(bf16x4*)&xb[(size_t)j * 256 + c0] = o;
    }
}

// ------------------- layer-3 x-aggregation (H=6 over x2 [N,256]) + att write
// xagg[j][h*256+c] = sum_e alpha[e,h]*x2[src][c];  xagg[j][1536+c] = x2[j][c]
__global__ __launch_bounds__(256) void agg3_k(
    const bf16_t* __restrict__ x2, const float* __restrict__ as_,
    const float* __restrict__ ad_, const int* __restrict__ offs,
    const int* __restrict__ csr_src, const int* __restrict__ csr_eid,
    bf16_t* __restrict__ xagg, float* __restrict__ att) {
    int j = blockIdx.x;
    int tid = threadIdx.x;  // 256
    int o0 = offs[j], deg = offs[j + 1] - o0;
    __shared__ float s_m[6], s_d[6], s_adj[6];
    __shared__ float s_alpha[64 * 6];
    __shared__ int s_src[64];
    __shared__ float s_red[4][6 * 256];  // 24 KB
    if (tid < 6) s_adj[tid] = ad_[j * 6 + tid];
    __syncthreads();
    if (tid < 64) {
        float mx[6], sm[6];
        #pragma unroll
        for (int hh = 0; hh < 6; ++hh) { mx[hh] = -3.4e38f; sm[hh] = 0.f; }
        for (int e = tid; e < deg; e += 64) {
            int s = csr_src[o0 + e];
            #pragma unroll
            for (int hh = 0; hh < 6; ++hh) {
                float v = leaky02(as_[s * 6 + hh] + s_adj[hh]);
                mx[hh] = fmaxf(mx[hh], v);
            }
        }
        #pragma unroll
        for (int off = 32; off; off >>= 1)
            #pragma unroll
            for (int hh = 0; hh < 6; ++hh) mx[hh] = fmaxf(mx[hh], __shfl_xor(mx[hh], off));
        for (int e = tid; e < deg; e += 64) {
            int s = csr_src[o0 + e];
            #pragma unroll
            for (int hh = 0; hh < 6; ++hh) {
                float v = leaky02(as_[s * 6 + hh] + s_adj[hh]);
                sm[hh] += __expf(v - mx[hh]);
            }
        }
        #pragma unroll
        for (int off = 32; off; off >>= 1)
            #pragma unroll
            for (int hh = 0; hh < 6; ++hh) sm[hh] += __shfl_xor(sm[hh], off);
        if (tid == 0) {
            #pragma unroll
            for (int hh = 0; hh < 6; ++hh) { s_m[hh] = mx[hh]; s_d[hh] = sm[hh]; }
        }
    }
    __syncthreads();
    int slot = tid >> 6;
    int c0 = (tid & 63) * 4;
    f32x4 acc[6] = {};
    for (int e0 = 0; e0 < deg; e0 += 64) {
        int ne = min(64, deg - e0);
        for (int i = tid; i < ne * 6; i += 256) {
            int e_l = i / 6, ah = i - e_l * 6;
            int p = o0 + e0 + e_l;
            int s = csr_src[p];
            if (ah == 0) s_src[e_l] = s;
            float v = leaky02(as_[s * 6 + ah] + s_adj[ah]);
            float al = __expf(v - s_m[ah]) / (s_d[ah] + 1e-16f);
            s_alpha[e_l * 6 + ah] = al;
            att[(size_t)csr_eid[p] * 6 + ah] = al;
        }
        __syncthreads();
        for (int e_l = slot; e_l < ne; e_l += 4) {
            int s = s_src[e_l];
            bf16x4 v = *(const bf16x4*)&x2[(size_t)s * 256 + c0];
            float f0 = (float)v[0], f1 = (float)v[1], f2 = (float)v[2], f3 = (float)v[3];
            #pragma unroll
            for (int hh = 0; hh < 6; ++hh) {
                float a = s_alpha[e_l * 6 + hh];
                acc[hh][0] += a * f0;
                acc[hh][1] += a * f1;
                acc[hh][2] += a * f2;
                acc[hh][3] += a * f3;
            }
        }
        __syncthreads();
    }
    #pragma unroll
    for (int hh = 0; hh < 6; ++hh) *(f32x4*)&s_red[slot][hh * 256 + c0] = acc[hh];
    __syncthreads();
    // final: thread = channel c (0..255); 6 heads + tail copy
    bf16_t* row = xagg + (size_t)j * 1792;
    #pragma unroll
    for (int hh = 0; hh < 6; ++hh) {
        int idx = hh * 256 + tid;
        float s = s_red[0][idx] + s_red[1][idx] + s_red[2][idx] + s_red[3][idx];
        row[idx] = (bf16_t)s;
    }
    row[1536 + tid] = x2[(size_t)j * 256 + tid];
}

// ---------------------------------------------------------------- BatchNorm
__global__ void bn_stats_k(const float* __restrict__ y, float* __restrict__ sums, int N) {
    int c = threadIdx.x;  // 128
    float s = 0.f, q = 0.f;
    for (int r = blockIdx.x; r < N; r += gridDim.x) {
        float v = y[(size_t)r * 128 + c];
        s += v;
        q += v * v;
    }
    atomicAdd(&sums[c], s);
    atomicAdd(&sums[128 + c], q);
}
__global__ void bn_scale_k(const float* __restrict__ sums, const float* __restrict__ gamma,
                           const float* __restrict__ beta, float* __restrict__ scale,
                           float* __restrict__ shift, int N) {
    int c = threadIdx.x;
    float mu = sums[c] / (float)N;
    float var = fmaxf(sums[128 + c] / (float)N - mu * mu, 0.f);
    float inv = rsqrtf(var + 1e-5f) * gamma[c];
    scale[c] = inv;
    shift[c] = beta[c] - mu * inv;
}

// ---------------------------------------------------------------- max pool
__device__ __forceinline__ unsigned f2key(float f) {
    unsigned b = __float_as_uint(f);
    return (b & 0x80000000u) ? ~b : (b | 0x80000000u);
}
__global__ void pool_init_k(unsigned* __restrict__ pool_u) {
    int i = blockIdx.x * 256 + threadIdx.x;
    if (i < N_GRAPHS * 128) pool_u[i] = f2key(-3.402823466e38f * 2.0f);
}
__global__ void norm_pool_k(const float* __restrict__ y, const float* __restrict__ scale,
                            const float* __restrict__ shift, const int* __restrict__ batch,
                            unsigned* __restrict__ pool_u, int N) {
    int idx = blockIdx.x * 256 + threadIdx.x;
    if (idx >= N * 128) return;
    int n = idx >> 7, c = idx & 127;
    float v = y[idx] * scale[c] + shift[c];
    atomicMax(&pool_u[batch[n] * 128 + c], f2key(v));
}
__global__ void pool_write_k(const unsigned* __restrict__ pool_u, float* __restrict__ out) {
    int i = blockIdx.x * 256 + threadIdx.x;
    if (i < N_GRAPHS * 128) {
        unsigned u = pool_u[i];
        unsigned b = (u & 0x80000000u) ? (u & 0x7FFFFFFFu) : ~u;
        out[i] = __uint_as_float(b);
    }
}

// ================================================================ launcher
extern "C" void kernel_launch(void* const* d_in, const int* in_sizes, int n_in,
                              void* d_out, int out_size, void* d_ws, size_t ws_size,
                              hipStream_t stream) {
    const int N = N_NODES, E = N_EDGES;
    const float* x_ppi = (const float*)d_in[0];
    const int* edge = (const int*)d_in[1];
    const int* batch = (const int*)d_in[2];
    const float* W1 = (const float*)d_in[3];
    const float* a_src1 = (const float*)d_in[4];
    const float* a_dst1 = (const float*)d_in[5];
    const float* b_gat1 = (const float*)d_in[6];
    const float* lw1 = (const float*)d_in[7];
    const float* lb1 = (const float*)d_in[8];
    const float* W2 = (const float*)d_in[9];
    const float* a_src2 = (const float*)d_in[10];
    const float* a_dst2 = (const float*)d_in[11];
    const float* b_gat2 = (const float*)d_in[12];
    const float* lw2 = (const float*)d_in[13];
    const float* lb2 = (const float*)d_in[14];
    const float* W3 = (const float*)d_in[15];
    const float* a_src3 = (const float*)d_in[16];
    const float* a_dst3 = (const float*)d_in[17];
    const float* b_gat3 = (const float*)d_in[18];
    const float* lw3 = (const float*)d_in[19];
    const float* lb3 = (const float*)d_in[20];
    const float* bn_gamma = (const float*)d_in[21];
    const float* bn_beta = (const float*)d_in[22];

    const int* src = edge;
    const int* dst = edge + E;

    size_t off = 0;
    auto alloc = [&](size_t bytes) {
        size_t o = off;
        off = (off + bytes + 255) & ~(size_t)255;
        return o;
    };
    char* ws = (char*)d_ws;
    bf16_t* xb = (bf16_t*)(ws + alloc((size_t)N * 256 * 2));
    // big region: xagg3 [N,1792] bf16; hb and lin alias its front (dead before
    // agg3_k writes xagg3)
    char* bigA = ws + alloc((size_t)N * 1792 * 2);
    bf16_t* xagg3 = (bf16_t*)bigA;
    bf16_t* hb = (bf16_t*)bigA;                                  // [N,256] bf16
    float* lin = (float*)(bigA + ((size_t)N * 256 * 2 + 255 & ~(size_t)255));  // [N,256] f32
    float* xagg1 = (float*)(ws + alloc((size_t)N * 40 * 4));
    float* y = (float*)(ws + alloc((size_t)N * 128 * 4));
    float* as_ = (float*)(ws + alloc((size_t)N * 6 * 4));
    float* ad_ = (float*)(ws + alloc((size_t)N * 6 * 4));
    int* deg = (int*)(ws + alloc((size_t)(N + 1) * 4));
    int* offs = (int*)(ws + alloc((size_t)(N + 1) * 4));
    int* cursor = (int*)(ws + alloc((size_t)(N + 1) * 4));
    int* csr_src = (int*)(ws + alloc((size_t)E * 4));
    int* csr_eid = (int*)(ws + alloc((size_t)E * 4));
    bf16_t* Wt2 = (bf16_t*)(ws + alloc((size_t)256 * 256 * 2));
    bf16_t* lwt2 = (bf16_t*)(ws + alloc((size_t)256 * 256 * 2));
    bf16_t* Bt3x = (bf16_t*)(ws + alloc((size_t)128 * 1792 * 2));
    float* B1 = (float*)(ws + alloc((size_t)40 * 256 * 4));
    float* bb1 = (float*)(ws + alloc(256 * 4));
    float* bb3 = (float*)(ws + alloc(128 * 4));
    float* WaT1 = (float*)(ws + alloc(64 * 4));
    float* WaT2 = (float*)(ws + alloc(2048 * 4));
    float* WaT3 = (float*)(ws + alloc(3072 * 4));
    float* bn_sums = (float*)(ws + alloc(256 * 4));
    float* bn_scale = (float*)(ws + alloc(128 * 4));
    float* bn_shift = (float*)(ws + alloc(128 * 4));
    unsigned* pool_u = (unsigned*)(ws + alloc((size_t)N_GRAPHS * 128 * 4));

    float* out_pool = (float*)d_out;
    float* out_att = (float*)d_out + N_GRAPHS * 128;

    // ---- CSR + weight prep (independent)
    hipMemsetAsync(deg, 0, (size_t)N * 4, stream);
    hist_k<<<(E + 255) / 256, 256, 0, stream>>>(dst, deg, E);
    scan_k<<<1, 1024, 0, stream>>>(deg, offs, cursor, N);
    scatter_k<<<(E + 255) / 256, 256, 0, stream>>>(src, dst, cursor, csr_src, csr_eid, E);
    wt_k<<<dim3(8, 8), 256, 0, stream>>>(W2, Wt2, 256, 256);
    wt_k<<<dim3(8, 8), 256, 0, stream>>>(lw2, lwt2, 256, 256);
    fold_k<<<1, 64, 0, stream>>>(W1, a_src1, a_dst1, WaT1, 8, 4, 64);
    fold_k<<<4, 64, 0, stream>>>(W2, a_src2, a_dst2, WaT2, 256, 4, 64);
    fold_k<<<4, 64, 0, stream>>>(W3, a_src3, a_dst3, WaT3, 256, 6, 128);
    b1prep_k<<<1, 256, 0, stream>>>(W1, lw1, b_gat1, lb1, B1, bb1);
    b3prep_k<<<128, 256, 0, stream>>>(W3, lw3, b_gat3, lb3, Bt3x, bb3);

    // ---- Layer 1: scores from x, aggregate x, one fused fp32 GEMM -> xb
    scores1_k<<<(N + 255) / 256, 256, 0, stream>>>(x_ppi, WaT1, as_, ad_, N);
    agg1_k<<<(N + 3) / 4, 256, 0, stream>>>(x_ppi, as_, ad_, offs, csr_src, xagg1);
    gemm_k<bf16_t, true><<<dim3(4, 313), 256, 0, stream>>>(xagg1, B1, xb, bb1, N, 256, 40);

    // ---- Layer 2 (256 -> 256, bf16 MFMA)
    gemm_bf16_k<bf16_t, false><<<dim3(2, 157), 256, 0, stream>>>(xb, Wt2, hb, nullptr,
                                                                 N, 256, 256);
    gemm_bf16_k<float, false><<<dim3(2, 157), 256, 0, stream>>>(xb, lwt2, lin, lb2,
                                                                N, 256, 256);
    scores_k<8><<<(N + 3) / 4, 256, 0, stream>>>(xb, WaT2, as_, ad_, N);
    agg_concat_k<<<N, 256, 0, stream>>>(hb, as_, ad_, offs, csr_src, lin, b_gat2, xb);

    // ---- Layer 3: scores, aggregate x2 per head (+att), one fused GEMM -> y
    scores_k<12><<<(N + 3) / 4, 256, 0, stream>>>(xb, WaT3, as_, ad_, N);
    agg3_k<<<N, 256, 0, stream>>>(xb, as_, ad_, offs, csr_src, csr_eid, xagg3, out_att);
    gemm_bf16_k<float, true><<<dim3(1, 157), 256, 0, stream>>>(xagg3, Bt3x, y, bb3,
                                                               N, 128, 1792);

    // ---- BatchNorm (training stats, fused sum+sumsq pass)
    hipMemsetAsync(bn_sums, 0, 256 * 4, stream);
    bn_stats_k<<<160, 128, 0, stream>>>(y, bn_sums, N);
    bn_scale_k<<<1, 128, 0, stream>>>(bn_sums, bn_gamma, bn_beta, bn_scale, bn_shift, N);

    // ---- normalize + global max pool
    pool_init_k<<<(N_GRAPHS * 128 + 255) / 256, 256, 0, stream>>>(pool_u);
    norm_pool_k<<<((size_t)N * 128 + 255) / 256, 256, 0, stream>>>(y, bn_scale, bn_shift, batch,
                                                                   pool_u, N);
    pool_write_k<<<(N_GRAPHS * 128 + 255) / 256, 256, 0, stream>>>(pool_u, out_pool);
}